// Round 8
// baseline (667.113 us; speedup 1.0000x reference)
//
#include <hip/hip_runtime.h>
#include <hip/hip_bf16.h>

typedef __bf16 bf16_t;
typedef __bf16 bf16x8 __attribute__((ext_vector_type(8)));
typedef float f32x16 __attribute__((ext_vector_type(16)));

#define B_DIM 8
#define LQ 1024
#define LK 1024
#define DD 512
#define NH 8
#define LB 2          // batches per chunk
#define NCH 4         // chunks

static __device__ __forceinline__ f32x16 mfma32(bf16x8 a, bf16x8 b, f32x16 c) {
  return __builtin_amdgcn_mfma_f32_32x32x16_bf16(a, b, c, 0, 0, 0);
}

// async global->LDS, 16B per lane (wave-uniform LDS base + lane*16)
static __device__ __forceinline__ void gld_lds16(const bf16_t* g, bf16_t* l) {
  __builtin_amdgcn_global_load_lds(
      (const __attribute__((address_space(1))) void*)g,
      (__attribute__((address_space(3))) void*)l, 16, 0, 0);
}

// ---------------- fp32 -> bf16 conversions ----------------
__global__ void cvt_pair(const float* __restrict__ s0, bf16_t* __restrict__ d0,
                         const float* __restrict__ s1, bf16_t* __restrict__ d1, int n) {
  const float* s = blockIdx.y ? s1 : s0;
  bf16_t* d = blockIdx.y ? d1 : d0;
  int i = (blockIdx.x * 256 + threadIdx.x) * 4;
  if (i < n) {
    const float4 f = *(const float4*)(s + i);
    bf16_t* p = d + i;
    p[0] = (bf16_t)f.x; p[1] = (bf16_t)f.y; p[2] = (bf16_t)f.z; p[3] = (bf16_t)f.w;
  }
}

__global__ void cvt_w4(const float* __restrict__ s0, const float* __restrict__ s1,
                       const float* __restrict__ s2, const float* __restrict__ s3,
                       bf16_t* __restrict__ d0, bf16_t* __restrict__ d1,
                       bf16_t* __restrict__ d2, bf16_t* __restrict__ d3, int n) {
  const float* s = (blockIdx.y == 0) ? s0 : (blockIdx.y == 1) ? s1
                  : (blockIdx.y == 2) ? s2 : s3;
  bf16_t* d = (blockIdx.y == 0) ? d0 : (blockIdx.y == 1) ? d1
             : (blockIdx.y == 2) ? d2 : d3;
  int i = (blockIdx.x * 256 + threadIdx.x) * 4;
  if (i < n) {
    const float4 f = *(const float4*)(s + i);
    bf16_t* p = d + i;
    p[0] = (bf16_t)f.x; p[1] = (bf16_t)f.y; p[2] = (bf16_t)f.z; p[3] = (bf16_t)f.w;
  }
}

// ---------------- GEMM mainloop: BK=64, XOR-swizzled LDS, 32x32x16 MFMA ------
// C-tile 128x128, 4 waves in 2x2; each wave owns 64x64 = 2x2 tiles of 32x32.
// LDS: slot s holds row r=s>>3, global col-chunk (s&7)^(r&7) (8 bf16/chunk).
// Same LDS traffic as 16x16 variant (16 ds_read_b128/wave per BK64) but 16 MFMA
// instead of 32 -> compute phase ~17% shorter (m119: 32x32 8.07cyc vs 16x16 4.85).
static __device__ __forceinline__ void gemm_core(
    const bf16_t* __restrict__ A, const bf16_t* __restrict__ B, int ld, int klen,
    int m0, int n0, bf16_t* As, bf16_t* Bs, f32x16 (&acc)[2][2])
{
  const int tid = threadIdx.x;
  const int wave = tid >> 6, lane = tid & 63;
  const int l31 = lane & 31, half = lane >> 5;
  const int wm = (wave & 1) * 64, wn = (wave >> 1) * 64;

  const int r0 = tid >> 3;        // + p*32 per pass
  const int c8s = tid & 7;        // stored chunk index
  bf16_t* Asl = As + tid * 8;
  bf16_t* Bsl = Bs + tid * 8;

  for (int k0 = 0; k0 < klen; k0 += 64) {
    __syncthreads();
#pragma unroll
    for (int p = 0; p < 4; ++p) {
      const int r = r0 + p * 32;
      const int gc = ((c8s ^ (r & 7)) * 8) + k0;
      gld_lds16(A + (size_t)(m0 + r) * ld + gc, Asl + p * 2048);
      gld_lds16(B + (size_t)(n0 + r) * ld + gc, Bsl + p * 2048);
    }
    __syncthreads();  // drains vmcnt
#pragma unroll
    for (int ks = 0; ks < 4; ++ks) {
      bf16x8 af[2], bfr[2];
#pragma unroll
      for (int i = 0; i < 2; ++i) {
        const int r = wm + i * 32 + l31;
        af[i] = *(const bf16x8*)&As[(r * 8 + ((ks * 2 + half) ^ (r & 7))) * 8];
      }
#pragma unroll
      for (int j = 0; j < 2; ++j) {
        const int r = wn + j * 32 + l31;
        bfr[j] = *(const bf16x8*)&Bs[(r * 8 + ((ks * 2 + half) ^ (r & 7))) * 8];
      }
#pragma unroll
      for (int i = 0; i < 2; ++i)
#pragma unroll
        for (int j = 0; j < 2; ++j)
          acc[i][j] = mfma32(af[i], bfr[j], acc[i][j]);
    }
  }
}

// 32x32 C/D layout: col = lane&31, row = (reg&3) + 8*(reg>>2) + 4*(lane>>5)
#define ROWL(rg, half) (((rg) & 3) + 8 * ((rg) >> 2) + 4 * (half))

// ---------------- fused Q/K/Vt projections ----------------
// grid (32, 3*LB*NH). blockIdx.y = role*16 + z, z = bb*NH+hh.
__global__ __launch_bounds__(256, 4) void gemm_qkv(
    const bf16_t* __restrict__ xcb, const bf16_t* __restrict__ scb,
    const bf16_t* __restrict__ wq, const bf16_t* __restrict__ wk,
    const bf16_t* __restrict__ wv,
    const float* __restrict__ bq, const float* __restrict__ bk,
    const float* __restrict__ bv,
    bf16_t* __restrict__ Qc, bf16_t* __restrict__ Kc, bf16_t* __restrict__ Vtc)
{
  const int role = blockIdx.y >> 4, z = blockIdx.y & 15;
  const int bb = z >> 3, hh = z & 7;
  const int tx = blockIdx.x;

  const bf16_t* A; const bf16_t* Bm; const float* bias; bf16_t* C;
  int m0, n0, ldc, bias_row;
  if (role == 0) {
    A = xcb + (size_t)bb * LQ * DD; Bm = wq + (size_t)hh * DD * DD;
    bias = bq + hh * DD; C = Qc + (size_t)z * LQ * DD;
    m0 = (tx >> 2) * 128; n0 = (tx & 3) * 128; ldc = DD; bias_row = 0;
  } else if (role == 1) {
    A = scb + (size_t)bb * LK * DD; Bm = wk + (size_t)hh * DD * DD;
    bias = bk + hh * DD; C = Kc + (size_t)z * LK * DD;
    m0 = (tx >> 2) * 128; n0 = (tx & 3) * 128; ldc = DD; bias_row = 0;
  } else {
    A = wv + (size_t)hh * DD * DD; Bm = scb + (size_t)bb * LK * DD;
    bias = bv + hh * DD; C = Vtc + (size_t)z * DD * LK;
    m0 = (tx & 3) * 128; n0 = (tx >> 2) * 128; ldc = LK; bias_row = 1;
  }

  __shared__ __align__(16) bf16_t As[128 * 64];
  __shared__ __align__(16) bf16_t Bs[128 * 64];
  f32x16 acc[2][2];
#pragma unroll
  for (int i = 0; i < 2; ++i)
#pragma unroll
    for (int j = 0; j < 2; ++j) acc[i][j] = (f32x16)(0.f);

  gemm_core(A, Bm, DD, DD, m0, n0, As, Bs, acc);

  const int tid = threadIdx.x, wave = tid >> 6, lane = tid & 63;
  const int l31 = lane & 31, half = lane >> 5;
  const int wm = (wave & 1) * 64, wn = (wave >> 1) * 64;
#pragma unroll
  for (int i = 0; i < 2; ++i)
#pragma unroll
    for (int j = 0; j < 2; ++j)
#pragma unroll
      for (int rg = 0; rg < 16; ++rg) {
        const int row = m0 + wm + i * 32 + ROWL(rg, half);
        const int col = n0 + wn + j * 32 + l31;
        const float v = acc[i][j][rg] + (bias_row ? bias[row] : bias[col]);
        C[(size_t)row * ldc + col] = (bf16_t)v;
      }
}

// ---------------- pass 1: S = exp(mask ? QK^T*scale : 0), rowsum partials ----
// grid (8, 8, LB*NH). rs layout: [z][ntile(8)][halfpair(2)][LQ] f32; slot =
// wave>>1 (waves 0/2 and 1/3 cover same rows, different col halves).
__global__ __launch_bounds__(256, 4) void gemm_qk(
    const bf16_t* __restrict__ Q, const bf16_t* __restrict__ K,
    const int* __restrict__ mask, bf16_t* __restrict__ S, float* __restrict__ rs)
{
  const int z = blockIdx.z, bb = z >> 3, nt = blockIdx.y;
  const bf16_t* Az = Q + (size_t)z * LQ * DD;
  const bf16_t* Bz = K + (size_t)z * LK * DD;
  bf16_t* Sz = S + (size_t)z * LQ * LK;
  const int* mz = mask + (size_t)bb * LQ * LK;

  const int m0 = blockIdx.x * 128, n0 = nt * 128;
  __shared__ __align__(16) bf16_t As[128 * 64];
  __shared__ __align__(16) bf16_t Bs[128 * 64];
  f32x16 acc[2][2];
#pragma unroll
  for (int i = 0; i < 2; ++i)
#pragma unroll
    for (int j = 0; j < 2; ++j) acc[i][j] = (f32x16)(0.f);

  gemm_core(Az, Bz, DD, DD, m0, n0, As, Bs, acc);

  const int tid = threadIdx.x, wave = tid >> 6, lane = tid & 63;
  const int l31 = lane & 31, half = lane >> 5;
  const int wm = (wave & 1) * 64, wn = (wave >> 1) * 64;
  float* rsz = rs + (((size_t)z * 8 + nt) * 2 + (wave >> 1)) * LQ;
  const float scale = 0.04419417382415922f;  // 1/sqrt(512)

#pragma unroll
  for (int i = 0; i < 2; ++i)
#pragma unroll
    for (int rg = 0; rg < 16; ++rg) {
      const int row = m0 + wm + i * 32 + ROWL(rg, half);
      float rsum = 0.f;
#pragma unroll
      for (int j = 0; j < 2; ++j) {
        const int col = n0 + wn + j * 32 + l31;
        const int mv = mz[(size_t)row * LK + col];
        const float p = mv ? __expf(acc[i][j][rg] * scale) : 0.f;
        rsum += p;
        Sz[(size_t)row * LK + col] = (bf16_t)p;
      }
      rsum += __shfl_xor(rsum, 1);
      rsum += __shfl_xor(rsum, 2);
      rsum += __shfl_xor(rsum, 4);
      rsum += __shfl_xor(rsum, 8);
      rsum += __shfl_xor(rsum, 16);
      if (l31 == 0) rsz[row] = rsum;   // two writers (half 0/1) -> distinct rows
    }
}

// ---------------- pass 2: ctx = (S * inv_rowsum) . V ----------------
// inv computed in-prologue from the 16 rs partials per row (no extra dispatch).
__global__ __launch_bounds__(256, 4) void gemm_pv(
    const bf16_t* __restrict__ S, const bf16_t* __restrict__ Vt,
    const float* __restrict__ rs, bf16_t* __restrict__ ctx)
{
  const int z = blockIdx.z, bb = z >> 3, hh = z & 7;
  const bf16_t* Az = S + (size_t)z * LQ * LK;
  const bf16_t* Bz = Vt + (size_t)z * DD * LK;
  bf16_t* Cz = ctx + (size_t)bb * LQ * (NH * DD) + (size_t)hh * DD;

  const int m0 = blockIdx.x * 128, n0 = blockIdx.y * 128;
  __shared__ __align__(16) bf16_t As[128 * 64];
  __shared__ __align__(16) bf16_t Bs[128 * 64];
  __shared__ float invs[128];

  const int tid = threadIdx.x;
  if (tid < 128) {   // rowsum reduce for this block's 128 rows
    const float* p = rs + (size_t)z * 16 * LQ + (m0 + tid);
    float tot = 0.f;
#pragma unroll
    for (int s = 0; s < 16; ++s) tot += p[s * LQ];
    invs[tid] = 1.f / tot;
  }
  // visibility guaranteed by gemm_core's internal barriers before epilogue

  f32x16 acc[2][2];
#pragma unroll
  for (int i = 0; i < 2; ++i)
#pragma unroll
    for (int j = 0; j < 2; ++j) acc[i][j] = (f32x16)(0.f);

  gemm_core(Az, Bz, LK, LK, m0, n0, As, Bs, acc);

  const int wave = tid >> 6, lane = tid & 63;
  const int l31 = lane & 31, half = lane >> 5;
  const int wm = (wave & 1) * 64, wn = (wave >> 1) * 64;

#pragma unroll
  for (int i = 0; i < 2; ++i)
#pragma unroll
    for (int rg = 0; rg < 16; ++rg) {
      const int lrow = wm + i * 32 + ROWL(rg, half);
      const float iv = invs[lrow];
#pragma unroll
      for (int j = 0; j < 2; ++j) {
        const int col = n0 + wn + j * 32 + l31;
        Cz[(size_t)(m0 + lrow) * (NH * DD) + col] = (bf16_t)(acc[i][j][rg] * iv);
      }
    }
}

// ---------------- out-projection, split-K=4 ----------------
// grid (64, 4, 4). partial[ks] : [8192,512] f32.
__global__ __launch_bounds__(256, 4) void gemm_outk(
    const bf16_t* __restrict__ ctx, const bf16_t* __restrict__ wp,
    float* __restrict__ partial)
{
  const int ks = blockIdx.z;
  const bf16_t* A = ctx + ks * 1024;
  const bf16_t* B = wp + ks * 1024;
  float* P = partial + (size_t)ks * B_DIM * LQ * DD;

  const int m0 = blockIdx.x * 128, n0 = blockIdx.y * 128;
  __shared__ __align__(16) bf16_t As[128 * 64];
  __shared__ __align__(16) bf16_t Bs[128 * 64];
  f32x16 acc[2][2];
#pragma unroll
  for (int i = 0; i < 2; ++i)
#pragma unroll
    for (int j = 0; j < 2; ++j) acc[i][j] = (f32x16)(0.f);

  gemm_core(A, B, NH * DD, 1024, m0, n0, As, Bs, acc);

  const int tid = threadIdx.x, wave = tid >> 6, lane = tid & 63;
  const int l31 = lane & 31, half = lane >> 5;
  const int wm = (wave & 1) * 64, wn = (wave >> 1) * 64;
#pragma unroll
  for (int i = 0; i < 2; ++i)
#pragma unroll
    for (int j = 0; j < 2; ++j)
#pragma unroll
      for (int rg = 0; rg < 16; ++rg) {
        const int row = m0 + wm + i * 32 + ROWL(rg, half);
        const int col = n0 + wn + j * 32 + l31;
        P[(size_t)row * DD + col] = acc[i][j][rg];
      }
}

__global__ void reduce_out(const float* __restrict__ p, const float* __restrict__ bp,
                           float* __restrict__ out) {
  const int N = B_DIM * LQ * DD;
  int i = (blockIdx.x * 256 + threadIdx.x) * 4;
  float4 a = *(const float4*)(p + i);
  float4 b = *(const float4*)(p + N + i);
  float4 c = *(const float4*)(p + 2 * N + i);
  float4 d = *(const float4*)(p + 3 * N + i);
  const float4 bb4 = *(const float4*)(bp + (i & 511));
  float4 r;
  r.x = a.x + b.x + c.x + d.x + bb4.x;
  r.y = a.y + b.y + c.y + d.y + bb4.y;
  r.z = a.z + b.z + c.z + d.z + bb4.z;
  r.w = a.w + b.w + c.w + d.w + bb4.w;
  *(float4*)(out + i) = r;
}

// ---------------- host launcher ----------------
extern "C" void kernel_launch(void* const* d_in, const int* in_sizes, int n_in,
                              void* d_out, int out_size, void* d_ws, size_t ws_size,
                              hipStream_t stream) {
  const float* x      = (const float*)d_in[0];
  const float* states = (const float*)d_in[1];
  const int*   mask   = (const int*)d_in[2];
  const float* Wq     = (const float*)d_in[3];
  const float* bq     = (const float*)d_in[4];
  const float* Wk     = (const float*)d_in[5];
  const float* bk     = (const float*)d_in[6];
  const float* Wv     = (const float*)d_in[7];
  const float* bv     = (const float*)d_in[8];
  const float* Wp     = (const float*)d_in[9];
  const float* bp     = (const float*)d_in[10];
  float* out = (float*)d_out;

  // Workspace layout (ends at exactly 167,772,160 B = 160 MiB, proven safe R2-R7):
  //   ctx 64MB @ 0 ; wqb/wkb/wvb 4MB each @ 64M..76M
  //   Qc 16MB @ 76M ; Kc 16MB @ 92M ; Vtc 16MB @ 108M
  //   S 32MB @ 124M ; xcb 2MB @ 156M ; scb 2MB @ 158M
  //   out-proj fp32 partials (64MB) reuse Kc/Vtc/S after chunks
  // d_out (16MB fp32) as scratch until reduce_out:
  //   rsum [16][8][2][LQ] f32 = 1MB @ +0 ; wpb bf16 4MB @ +1MB
  char* ws = (char*)d_ws;
  bf16_t* ctxb = (bf16_t*)(ws + 0);
  bf16_t* wqb  = (bf16_t*)(ws + 67108864);
  bf16_t* wkb  = (bf16_t*)(ws + 71303168);
  bf16_t* wvb  = (bf16_t*)(ws + 75497472);
  bf16_t* Qc   = (bf16_t*)(ws + 79691776);
  bf16_t* Kc   = (bf16_t*)(ws + 96468992);
  bf16_t* Vtc  = (bf16_t*)(ws + 113246208);
  bf16_t* Sb   = (bf16_t*)(ws + 130023424);
  bf16_t* xcb  = (bf16_t*)(ws + 163577856);
  bf16_t* scb  = (bf16_t*)(ws + 165675008);
  float*  pbuf = (float*)(ws + 96468992);          // dead Kc/Vtc/S region after chunks
  float*  rsum = out;                              // 1MB in d_out
  bf16_t* wpb  = (bf16_t*)((char*)d_out + 1048576); // 4MB in d_out, dead before reduce_out

  const int n_w = NH * DD * DD;          // 2,097,152
  const int n_xc = LB * LQ * DD;         // 1,048,576 per chunk

  cvt_w4<<<dim3(n_w / 1024, 4), 256, 0, stream>>>(
      Wq, Wk, Wv, Wp, wqb, wkb, wvb, wpb, n_w);

  for (int c = 0; c < NCH; ++c) {
    const float* xc = x + (size_t)c * LB * LQ * DD;
    const float* sc = states + (size_t)c * LB * LK * DD;
    const int* mc = mask + (size_t)c * LB * LQ * LK;
    bf16_t* ctxc = ctxb + (size_t)c * LB * LQ * (NH * DD);

    cvt_pair<<<dim3(n_xc / 1024, 2), 256, 0, stream>>>(xc, xcb, sc, scb, n_xc);

    // fused Q/K/Vt projections: 1536 blocks = 6 blocks/CU
    gemm_qkv<<<dim3(32, 3 * LB * NH), 256, 0, stream>>>(
        xcb, scb, wqb, wkb, wvb, bq, bk, bv, Qc, Kc, Vtc);

    // attention as two GEMM passes
    gemm_qk<<<dim3(8, 8, LB * NH), 256, 0, stream>>>(Qc, Kc, mc, Sb, rsum);
    gemm_pv<<<dim3(8, 4, LB * NH), 256, 0, stream>>>(Sb, Vtc, rsum, ctxc);
  }

  // out = ctx @ Wp^T + bp : split-K=4 (1024 blocks) + reduce
  gemm_outk<<<dim3(64, 4, 4), 256, 0, stream>>>(ctxb, wpb, pbuf);
  reduce_out<<<(B_DIM * LQ * DD) / 1024, 256, 0, stream>>>(pbuf, bp, out);
}

// Round 9
// 622.467 us; speedup vs baseline: 1.0717x; 1.0717x over previous
//
#include <hip/hip_runtime.h>
#include <hip/hip_bf16.h>

typedef __bf16 bf16_t;
typedef __bf16 bf16x8 __attribute__((ext_vector_type(8)));
typedef float f32x4 __attribute__((ext_vector_type(4)));

#define B_DIM 8
#define LQ 1024
#define LK 1024
#define DD 512
#define NH 8
#define LB 2          // batches per chunk
#define NCH 4         // chunks

static __device__ __forceinline__ f32x4 mfma_bf16(bf16x8 a, bf16x8 b, f32x4 c) {
  return __builtin_amdgcn_mfma_f32_16x16x32_bf16(a, b, c, 0, 0, 0);
}

// async global->LDS, 16B per lane (wave-uniform LDS base + lane*16)
static __device__ __forceinline__ void gld_lds16(const bf16_t* g, bf16_t* l) {
  __builtin_amdgcn_global_load_lds(
      (const __attribute__((address_space(1))) void*)g,
      (__attribute__((address_space(3))) void*)l, 16, 0, 0);
}

// ---------------- all fp32 -> bf16 conversions, one dispatch ----------------
__global__ void cvt_all(const float* __restrict__ s0, const float* __restrict__ s1,
                        const float* __restrict__ s2, const float* __restrict__ s3,
                        const float* __restrict__ s4, const float* __restrict__ s5,
                        bf16_t* __restrict__ d0, bf16_t* __restrict__ d1,
                        bf16_t* __restrict__ d2, bf16_t* __restrict__ d3,
                        bf16_t* __restrict__ d4, bf16_t* __restrict__ d5,
                        int n_w, int n_x) {
  const int slot = blockIdx.y;
  const float* s; bf16_t* d; int n;
  switch (slot) {
    case 0: s = s0; d = d0; n = n_w; break;
    case 1: s = s1; d = d1; n = n_w; break;
    case 2: s = s2; d = d2; n = n_w; break;
    case 3: s = s3; d = d3; n = n_w; break;
    case 4: s = s4; d = d4; n = n_x; break;
    default: s = s5; d = d5; n = n_x; break;
  }
  int i = (blockIdx.x * 256 + threadIdx.x) * 4;
  if (i < n) {
    const float4 f = *(const float4*)(s + i);
    bf16_t* p = d + i;
    p[0] = (bf16_t)f.x; p[1] = (bf16_t)f.y; p[2] = (bf16_t)f.z; p[3] = (bf16_t)f.w;
  }
}

// ---------------- GEMM mainloop: BK=64, XOR-swizzled LDS, 16x16x32 MFMA ------
// (R7 core, measured 0 bank conflicts; 32x32 frags are structurally 4-way
// conflicted at 128B row pitch — reverted in R9.)
// LDS: slot s holds row r=s>>3, global col-chunk (s&7)^(r&7) (8 bf16/chunk).
static __device__ __forceinline__ void gemm_core(
    const bf16_t* __restrict__ A, const bf16_t* __restrict__ B, int ld, int klen,
    int m0, int n0, bf16_t* As, bf16_t* Bs, f32x4 (&acc)[4][4])
{
  const int tid = threadIdx.x;
  const int wave = tid >> 6, lane = tid & 63;
  const int l15 = lane & 15, quad = lane >> 4;
  const int wm = (wave & 1) * 64, wn = (wave >> 1) * 64;

  const int r0 = tid >> 3;        // + p*32 per pass
  const int c8s = tid & 7;        // stored chunk index
  bf16_t* Asl = As + tid * 8;
  bf16_t* Bsl = Bs + tid * 8;

  for (int k0 = 0; k0 < klen; k0 += 64) {
    __syncthreads();
#pragma unroll
    for (int p = 0; p < 4; ++p) {
      const int r = r0 + p * 32;
      const int gc = ((c8s ^ (r & 7)) * 8) + k0;
      gld_lds16(A + (size_t)(m0 + r) * ld + gc, Asl + p * 2048);
      gld_lds16(B + (size_t)(n0 + r) * ld + gc, Bsl + p * 2048);
    }
    __syncthreads();  // drains vmcnt
#pragma unroll
    for (int ks = 0; ks < 2; ++ks) {
      bf16x8 af[4], bfr[4];
#pragma unroll
      for (int i = 0; i < 4; ++i) {
        const int r = wm + i * 16 + l15;
        af[i] = *(const bf16x8*)&As[(r * 8 + ((ks * 4 + quad) ^ (r & 7))) * 8];
      }
#pragma unroll
      for (int j = 0; j < 4; ++j) {
        const int r = wn + j * 16 + l15;
        bfr[j] = *(const bf16x8*)&Bs[(r * 8 + ((ks * 4 + quad) ^ (r & 7))) * 8];
      }
#pragma unroll
      for (int i = 0; i < 4; ++i)
#pragma unroll
        for (int j = 0; j < 4; ++j)
          acc[i][j] = mfma_bf16(af[i], bfr[j], acc[i][j]);
    }
  }
}

// ---------------- fused Q/K/Vt projections ----------------
// grid (4, 48, 8): x = n-tile (B-strip dim, fastest -> same-XCD reuse of the
// shared weight strip across the 8 m-tiles in z), y = role*16 + z.
__global__ __launch_bounds__(256, 4) void gemm_qkv(
    const bf16_t* __restrict__ xcb, const bf16_t* __restrict__ scb,
    const bf16_t* __restrict__ wq, const bf16_t* __restrict__ wk,
    const bf16_t* __restrict__ wv,
    const float* __restrict__ bq, const float* __restrict__ bk,
    const float* __restrict__ bv,
    bf16_t* __restrict__ Qc, bf16_t* __restrict__ Kc, bf16_t* __restrict__ Vtc)
{
  const int role = blockIdx.y >> 4, z = blockIdx.y & 15;
  const int bb = z >> 3, hh = z & 7;

  const bf16_t* A; const bf16_t* Bm; const float* bias; bf16_t* C;
  int m0, n0, ldc, bias_row;
  if (role == 0) {
    A = xcb + (size_t)bb * LQ * DD; Bm = wq + (size_t)hh * DD * DD;
    bias = bq + hh * DD; C = Qc + (size_t)z * LQ * DD;
    m0 = blockIdx.z * 128; n0 = blockIdx.x * 128; ldc = DD; bias_row = 0;
  } else if (role == 1) {
    A = scb + (size_t)bb * LK * DD; Bm = wk + (size_t)hh * DD * DD;
    bias = bk + hh * DD; C = Kc + (size_t)z * LK * DD;
    m0 = blockIdx.z * 128; n0 = blockIdx.x * 128; ldc = DD; bias_row = 0;
  } else {
    A = wv + (size_t)hh * DD * DD; Bm = scb + (size_t)bb * LK * DD;
    bias = bv + hh * DD; C = Vtc + (size_t)z * DD * LK;
    m0 = blockIdx.x * 128; n0 = blockIdx.z * 128; ldc = LK; bias_row = 1;
  }

  __shared__ __align__(16) bf16_t As[128 * 64];
  __shared__ __align__(16) bf16_t Bs[128 * 64];
  f32x4 acc[4][4];
#pragma unroll
  for (int i = 0; i < 4; ++i)
#pragma unroll
    for (int j = 0; j < 4; ++j) acc[i][j] = (f32x4){0.f, 0.f, 0.f, 0.f};

  gemm_core(A, Bm, DD, DD, m0, n0, As, Bs, acc);

  const int tid = threadIdx.x, wave = tid >> 6, lane = tid & 63;
  const int l15 = lane & 15, quad = lane >> 4;
  const int wm = (wave & 1) * 64, wn = (wave >> 1) * 64;
#pragma unroll
  for (int i = 0; i < 4; ++i)
#pragma unroll
    for (int j = 0; j < 4; ++j)
#pragma unroll
      for (int r = 0; r < 4; ++r) {
        const int row = m0 + wm + i * 16 + quad * 4 + r;
        const int col = n0 + wn + j * 16 + l15;
        const float v = acc[i][j][r] + (bias_row ? bias[row] : bias[col]);
        C[(size_t)row * ldc + col] = (bf16_t)v;
      }
}

// ---------------- pass 1: S = exp(mask ? QK^T*scale : 0), rowsum partials ----
// grid (8 nt, 8 mt, 16 z): nt fastest -> the 8 m-tiles sharing a K n-strip land
// on the same XCD. rs layout: [z][nt(8)][half(2)][LQ] f32; half = wave>>1.
__global__ __launch_bounds__(256, 4) void gemm_qk(
    const bf16_t* __restrict__ Q, const bf16_t* __restrict__ K,
    const int* __restrict__ mask, bf16_t* __restrict__ S, float* __restrict__ rs)
{
  const int z = blockIdx.z, bb = z >> 3, nt = blockIdx.x;
  const bf16_t* Az = Q + (size_t)z * LQ * DD;
  const bf16_t* Bz = K + (size_t)z * LK * DD;
  bf16_t* Sz = S + (size_t)z * LQ * LK;
  const int* mz = mask + (size_t)bb * LQ * LK;

  const int m0 = blockIdx.y * 128, n0 = nt * 128;
  __shared__ __align__(16) bf16_t As[128 * 64];
  __shared__ __align__(16) bf16_t Bs[128 * 64];
  f32x4 acc[4][4];
#pragma unroll
  for (int i = 0; i < 4; ++i)
#pragma unroll
    for (int j = 0; j < 4; ++j) acc[i][j] = (f32x4){0.f, 0.f, 0.f, 0.f};

  gemm_core(Az, Bz, DD, DD, m0, n0, As, Bs, acc);

  const int tid = threadIdx.x, wave = tid >> 6, lane = tid & 63;
  const int l15 = lane & 15, quad = lane >> 4;
  const int wm = (wave & 1) * 64, wn = (wave >> 1) * 64;
  float* rsz = rs + (((size_t)z * 8 + nt) * 2 + (wave >> 1)) * LQ;
  const float scale = 0.04419417382415922f;  // 1/sqrt(512)

#pragma unroll
  for (int i = 0; i < 4; ++i)
#pragma unroll
    for (int r = 0; r < 4; ++r) {
      const int row = m0 + wm + i * 16 + quad * 4 + r;
      float rsum = 0.f;
#pragma unroll
      for (int j = 0; j < 4; ++j) {
        const int col = n0 + wn + j * 16 + l15;
        const int mv = mz[(size_t)row * LK + col];
        const float p = mv ? __expf(acc[i][j][r] * scale) : 0.f;
        rsum += p;
        Sz[(size_t)row * LK + col] = (bf16_t)p;
      }
      rsum += __shfl_xor(rsum, 1);
      rsum += __shfl_xor(rsum, 2);
      rsum += __shfl_xor(rsum, 4);
      rsum += __shfl_xor(rsum, 8);
      if (l15 == 0) rsz[row] = rsum;   // block+half-owned slot, no race
    }
}

// ---------------- pass 2: ctx = (S * inv_rowsum) . V ----------------
// grid (4 nt, 8 mt, 16 z): nt fastest for Vt-strip XCD locality.
// inv computed in-prologue from the 16 rs partials per row.
__global__ __launch_bounds__(256, 4) void gemm_pv(
    const bf16_t* __restrict__ S, const bf16_t* __restrict__ Vt,
    const float* __restrict__ rs, bf16_t* __restrict__ ctx)
{
  const int z = blockIdx.z, bb = z >> 3, hh = z & 7;
  const bf16_t* Az = S + (size_t)z * LQ * LK;
  const bf16_t* Bz = Vt + (size_t)z * DD * LK;
  bf16_t* Cz = ctx + (size_t)bb * LQ * (NH * DD) + (size_t)hh * DD;

  const int m0 = blockIdx.y * 128, n0 = blockIdx.x * 128;
  __shared__ __align__(16) bf16_t As[128 * 64];
  __shared__ __align__(16) bf16_t Bs[128 * 64];
  __shared__ float invs[128];

  const int tid = threadIdx.x;
  if (tid < 128) {   // rowsum reduce for this block's 128 rows
    const float* p = rs + (size_t)z * 16 * LQ + (m0 + tid);
    float tot = 0.f;
#pragma unroll
    for (int s = 0; s < 16; ++s) tot += p[s * LQ];
    invs[tid] = 1.f / tot;
  }
  // visibility guaranteed by gemm_core's internal barriers before epilogue

  f32x4 acc[4][4];
#pragma unroll
  for (int i = 0; i < 4; ++i)
#pragma unroll
    for (int j = 0; j < 4; ++j) acc[i][j] = (f32x4){0.f, 0.f, 0.f, 0.f};

  gemm_core(Az, Bz, LK, LK, m0, n0, As, Bs, acc);

  const int wave = tid >> 6, lane = tid & 63;
  const int l15 = lane & 15, quad = lane >> 4;
  const int wm = (wave & 1) * 64, wn = (wave >> 1) * 64;

#pragma unroll
  for (int i = 0; i < 4; ++i)
#pragma unroll
    for (int r = 0; r < 4; ++r) {
      const int lrow = wm + i * 16 + quad * 4 + r;
      const float iv = invs[lrow];
#pragma unroll
      for (int j = 0; j < 4; ++j) {
        const int col = n0 + wn + j * 16 + l15;
        Cz[(size_t)(m0 + lrow) * (NH * DD) + col] = (bf16_t)(acc[i][j][r] * iv);
      }
    }
}

// ---------------- out-projection, split-K=4 ----------------
// grid (4 nt, 64 mt, 4 ks): nt fastest for wp-strip XCD locality.
__global__ __launch_bounds__(256, 4) void gemm_outk(
    const bf16_t* __restrict__ ctx, const bf16_t* __restrict__ wp,
    float* __restrict__ partial)
{
  const int ks = blockIdx.z;
  const bf16_t* A = ctx + ks * 1024;
  const bf16_t* B = wp + ks * 1024;
  float* P = partial + (size_t)ks * B_DIM * LQ * DD;

  const int m0 = blockIdx.y * 128, n0 = blockIdx.x * 128;
  __shared__ __align__(16) bf16_t As[128 * 64];
  __shared__ __align__(16) bf16_t Bs[128 * 64];
  f32x4 acc[4][4];
#pragma unroll
  for (int i = 0; i < 4; ++i)
#pragma unroll
    for (int j = 0; j < 4; ++j) acc[i][j] = (f32x4){0.f, 0.f, 0.f, 0.f};

  gemm_core(A, B, NH * DD, 1024, m0, n0, As, Bs, acc);

  const int tid = threadIdx.x, wave = tid >> 6, lane = tid & 63;
  const int l15 = lane & 15, quad = lane >> 4;
  const int wm = (wave & 1) * 64, wn = (wave >> 1) * 64;
#pragma unroll
  for (int i = 0; i < 4; ++i)
#pragma unroll
    for (int j = 0; j < 4; ++j)
#pragma unroll
      for (int r = 0; r < 4; ++r) {
        const int row = m0 + wm + i * 16 + quad * 4 + r;
        const int col = n0 + wn + j * 16 + l15;
        P[(size_t)row * DD + col] = acc[i][j][r];
      }
}

__global__ void reduce_out(const float* __restrict__ p, const float* __restrict__ bp,
                           float* __restrict__ out) {
  const int N = B_DIM * LQ * DD;
  int i = (blockIdx.x * 256 + threadIdx.x) * 4;
  float4 a = *(const float4*)(p + i);
  float4 b = *(const float4*)(p + N + i);
  float4 c = *(const float4*)(p + 2 * N + i);
  float4 d = *(const float4*)(p + 3 * N + i);
  const float4 bb4 = *(const float4*)(bp + (i & 511));
  float4 r;
  r.x = a.x + b.x + c.x + d.x + bb4.x;
  r.y = a.y + b.y + c.y + d.y + bb4.y;
  r.z = a.z + b.z + c.z + d.z + bb4.z;
  r.w = a.w + b.w + c.w + d.w + bb4.w;
  *(float4*)(out + i) = r;
}

// ---------------- host launcher ----------------
extern "C" void kernel_launch(void* const* d_in, const int* in_sizes, int n_in,
                              void* d_out, int out_size, void* d_ws, size_t ws_size,
                              hipStream_t stream) {
  const float* x      = (const float*)d_in[0];
  const float* states = (const float*)d_in[1];
  const int*   mask   = (const int*)d_in[2];
  const float* Wq     = (const float*)d_in[3];
  const float* bq     = (const float*)d_in[4];
  const float* Wk     = (const float*)d_in[5];
  const float* bk     = (const float*)d_in[6];
  const float* Wv     = (const float*)d_in[7];
  const float* bv     = (const float*)d_in[8];
  const float* Wp     = (const float*)d_in[9];
  const float* bp     = (const float*)d_in[10];
  float* out = (float*)d_out;

  // Workspace (max offset 172,015,616 > no! recompute): layout below ends at
  // 164,626,432 B <= 167,772,160 B proven safe:
  //   ctx 64MB @ 0 ; wqb/wkb/wvb 4MB each @ 64M..76M
  //   Qc 16MB @ 76M ; Kc 16MB @ 92M ; Vtc 16MB @ 108M
  //   S 32MB @ 124M ; sb (full states bf16) 8MB @ 156M
  //   out-proj fp32 partials (64MB) reuse Kc/Vtc/S after chunks
  // d_out (16MB fp32) as scratch until reduce_out overwrites all of it:
  //   rsum 1MB @ +0 ; wpb bf16 4MB @ +1MB ; xb (full x bf16) 8MB @ +5MB
  char* ws = (char*)d_ws;
  bf16_t* ctxb = (bf16_t*)(ws + 0);
  bf16_t* wqb  = (bf16_t*)(ws + 67108864);
  bf16_t* wkb  = (bf16_t*)(ws + 71303168);
  bf16_t* wvb  = (bf16_t*)(ws + 75497472);
  bf16_t* Qc   = (bf16_t*)(ws + 79691776);
  bf16_t* Kc   = (bf16_t*)(ws + 96468992);
  bf16_t* Vtc  = (bf16_t*)(ws + 113246208);
  bf16_t* Sb   = (bf16_t*)(ws + 130023424);
  bf16_t* sbf  = (bf16_t*)(ws + 163577856);
  float*  pbuf = (float*)(ws + 96468992);           // dead Kc/Vtc/S after chunks
  float*  rsum = out;                               // 1MB
  bf16_t* wpb  = (bf16_t*)((char*)d_out + 1048576); // 4MB
  bf16_t* xbf  = (bf16_t*)((char*)d_out + 5242880); // 8MB

  const int n_w = NH * DD * DD;          // 2,097,152
  const int n_x = B_DIM * LQ * DD;       // 4,194,304

  // all conversions in one dispatch
  cvt_all<<<dim3(n_x / 1024, 6), 256, 0, stream>>>(
      Wq, Wk, Wv, Wp, x, states, wqb, wkb, wvb, wpb, xbf, sbf, n_w, n_x);

  for (int c = 0; c < NCH; ++c) {
    const bf16_t* xc = xbf + (size_t)c * LB * LQ * DD;
    const bf16_t* sc = sbf + (size_t)c * LB * LK * DD;
    const int* mc = mask + (size_t)c * LB * LQ * LK;
    bf16_t* ctxc = ctxb + (size_t)c * LB * LQ * (NH * DD);

    gemm_qkv<<<dim3(4, 48, 8), 256, 0, stream>>>(
        xc, sc, wqb, wkb, wvb, bq, bk, bv, Qc, Kc, Vtc);

    gemm_qk<<<dim3(8, 8, LB * NH), 256, 0, stream>>>(Qc, Kc, mc, Sb, rsum);
    gemm_pv<<<dim3(4, 8, LB * NH), 256, 0, stream>>>(Sb, Vtc, rsum, ctxc);
  }

  // out = ctx @ Wp^T + bp : split-K=4 (1024 blocks) + reduce
  gemm_outk<<<dim3(4, 64, 4), 256, 0, stream>>>(ctxb, wpb, pbuf);
  reduce_out<<<(B_DIM * LQ * DD) / 1024, 256, 0, stream>>>(pbuf, bp, out);
}

// Round 10
// 603.767 us; speedup vs baseline: 1.1049x; 1.0310x over previous
//
#include <hip/hip_runtime.h>
#include <hip/hip_bf16.h>

typedef __bf16 bf16_t;
typedef __bf16 bf16x8 __attribute__((ext_vector_type(8)));
typedef float f32x4 __attribute__((ext_vector_type(4)));

#define B_DIM 8
#define LQ 1024
#define LK 1024
#define DD 512
#define NH 8
#define LB 2          // batches per chunk
#define NCH 4         // chunks

static __device__ __forceinline__ f32x4 mfma_bf16(bf16x8 a, bf16x8 b, f32x4 c) {
  return __builtin_amdgcn_mfma_f32_16x16x32_bf16(a, b, c, 0, 0, 0);
}

// async global->LDS, 16B per lane (wave-uniform LDS base + lane*16)
static __device__ __forceinline__ void gld_lds16(const bf16_t* g, bf16_t* l) {
  __builtin_amdgcn_global_load_lds(
      (const __attribute__((address_space(1))) void*)g,
      (__attribute__((address_space(3))) void*)l, 16, 0, 0);
}

// ---------------- all fp32 -> bf16 conversions, one dispatch ----------------
__global__ void cvt_all(const float* __restrict__ s0, const float* __restrict__ s1,
                        const float* __restrict__ s2, const float* __restrict__ s3,
                        const float* __restrict__ s4, const float* __restrict__ s5,
                        bf16_t* __restrict__ d0, bf16_t* __restrict__ d1,
                        bf16_t* __restrict__ d2, bf16_t* __restrict__ d3,
                        bf16_t* __restrict__ d4, bf16_t* __restrict__ d5,
                        int n_w, int n_x) {
  const int slot = blockIdx.y;
  const float* s; bf16_t* d; int n;
  switch (slot) {
    case 0: s = s0; d = d0; n = n_w; break;
    case 1: s = s1; d = d1; n = n_w; break;
    case 2: s = s2; d = d2; n = n_w; break;
    case 3: s = s3; d = d3; n = n_w; break;
    case 4: s = s4; d = d4; n = n_x; break;
    default: s = s5; d = d5; n = n_x; break;
  }
  int i = (blockIdx.x * 256 + threadIdx.x) * 4;
  if (i < n) {
    const float4 f = *(const float4*)(s + i);
    bf16_t* p = d + i;
    p[0] = (bf16_t)f.x; p[1] = (bf16_t)f.y; p[2] = (bf16_t)f.z; p[3] = (bf16_t)f.w;
  }
}

// ---------------- GEMM mainloop: BK=64, XOR-swizzled LDS, 16x16x32 MFMA ------
// (R7 core, measured 0 bank conflicts.)
// LDS: slot s holds row r=s>>3, global col-chunk (s&7)^(r&7) (8 bf16/chunk).
static __device__ __forceinline__ void gemm_core(
    const bf16_t* __restrict__ A, const bf16_t* __restrict__ B, int ld, int klen,
    int m0, int n0, bf16_t* As, bf16_t* Bs, f32x4 (&acc)[4][4])
{
  const int tid = threadIdx.x;
  const int wave = tid >> 6, lane = tid & 63;
  const int l15 = lane & 15, quad = lane >> 4;
  const int wm = (wave & 1) * 64, wn = (wave >> 1) * 64;

  const int r0 = tid >> 3;        // + p*32 per pass
  const int c8s = tid & 7;        // stored chunk index
  bf16_t* Asl = As + tid * 8;
  bf16_t* Bsl = Bs + tid * 8;

  for (int k0 = 0; k0 < klen; k0 += 64) {
    __syncthreads();
#pragma unroll
    for (int p = 0; p < 4; ++p) {
      const int r = r0 + p * 32;
      const int gc = ((c8s ^ (r & 7)) * 8) + k0;
      gld_lds16(A + (size_t)(m0 + r) * ld + gc, Asl + p * 2048);
      gld_lds16(B + (size_t)(n0 + r) * ld + gc, Bsl + p * 2048);
    }
    __syncthreads();  // drains vmcnt
#pragma unroll
    for (int ks = 0; ks < 2; ++ks) {
      bf16x8 af[4], bfr[4];
#pragma unroll
      for (int i = 0; i < 4; ++i) {
        const int r = wm + i * 16 + l15;
        af[i] = *(const bf16x8*)&As[(r * 8 + ((ks * 4 + quad) ^ (r & 7))) * 8];
      }
#pragma unroll
      for (int j = 0; j < 4; ++j) {
        const int r = wn + j * 16 + l15;
        bfr[j] = *(const bf16x8*)&Bs[(r * 8 + ((ks * 4 + quad) ^ (r & 7))) * 8];
      }
#pragma unroll
      for (int i = 0; i < 4; ++i)
#pragma unroll
        for (int j = 0; j < 4; ++j)
          acc[i][j] = mfma_bf16(af[i], bfr[j], acc[i][j]);
    }
  }
}

// ---------------- fused Q/K/Vt projections (R7 grid: (32, 48)) ----------------
// blockIdx.y = role*16 + z, z = bb*NH+hh. tx: n fastest (period 4).
__global__ __launch_bounds__(256, 4) void gemm_qkv(
    const bf16_t* __restrict__ xcb, const bf16_t* __restrict__ scb,
    const bf16_t* __restrict__ wq, const bf16_t* __restrict__ wk,
    const bf16_t* __restrict__ wv,
    const float* __restrict__ bq, const float* __restrict__ bk,
    const float* __restrict__ bv,
    bf16_t* __restrict__ Qc, bf16_t* __restrict__ Kc, bf16_t* __restrict__ Vtc)
{
  const int role = blockIdx.y >> 4, z = blockIdx.y & 15;
  const int bb = z >> 3, hh = z & 7;
  const int tx = blockIdx.x;

  const bf16_t* A; const bf16_t* Bm; const float* bias; bf16_t* C;
  int m0, n0, ldc, bias_row;
  if (role == 0) {
    A = xcb + (size_t)bb * LQ * DD; Bm = wq + (size_t)hh * DD * DD;
    bias = bq + hh * DD; C = Qc + (size_t)z * LQ * DD;
    m0 = (tx >> 2) * 128; n0 = (tx & 3) * 128; ldc = DD; bias_row = 0;
  } else if (role == 1) {
    A = scb + (size_t)bb * LK * DD; Bm = wk + (size_t)hh * DD * DD;
    bias = bk + hh * DD; C = Kc + (size_t)z * LK * DD;
    m0 = (tx >> 2) * 128; n0 = (tx & 3) * 128; ldc = DD; bias_row = 0;
  } else {
    A = wv + (size_t)hh * DD * DD; Bm = scb + (size_t)bb * LK * DD;
    bias = bv + hh * DD; C = Vtc + (size_t)z * DD * LK;
    m0 = (tx & 3) * 128; n0 = (tx >> 2) * 128; ldc = LK; bias_row = 1;
  }

  __shared__ __align__(16) bf16_t As[128 * 64];
  __shared__ __align__(16) bf16_t Bs[128 * 64];
  f32x4 acc[4][4];
#pragma unroll
  for (int i = 0; i < 4; ++i)
#pragma unroll
    for (int j = 0; j < 4; ++j) acc[i][j] = (f32x4){0.f, 0.f, 0.f, 0.f};

  gemm_core(A, Bm, DD, DD, m0, n0, As, Bs, acc);

  const int tid = threadIdx.x, wave = tid >> 6, lane = tid & 63;
  const int l15 = lane & 15, quad = lane >> 4;
  const int wm = (wave & 1) * 64, wn = (wave >> 1) * 64;
#pragma unroll
  for (int i = 0; i < 4; ++i)
#pragma unroll
    for (int j = 0; j < 4; ++j)
#pragma unroll
      for (int r = 0; r < 4; ++r) {
        const int row = m0 + wm + i * 16 + quad * 4 + r;
        const int col = n0 + wn + j * 16 + l15;
        const float v = acc[i][j][r] + (bias_row ? bias[row] : bias[col]);
        C[(size_t)row * ldc + col] = (bf16_t)v;
      }
}

// ---------------- pass 1: S = exp(mask ? QK^T*scale : 0), rowsum partials ----
// R7 grid (8 mt, 8 nt, 16 z). rs: [z][nt(8)][half(2)][LQ] f32; half = wave>>1.
__global__ __launch_bounds__(256, 4) void gemm_qk(
    const bf16_t* __restrict__ Q, const bf16_t* __restrict__ K,
    const int* __restrict__ mask, bf16_t* __restrict__ S, float* __restrict__ rs)
{
  const int z = blockIdx.z, bb = z >> 3, nt = blockIdx.y;
  const bf16_t* Az = Q + (size_t)z * LQ * DD;
  const bf16_t* Bz = K + (size_t)z * LK * DD;
  bf16_t* Sz = S + (size_t)z * LQ * LK;
  const int* mz = mask + (size_t)bb * LQ * LK;

  const int m0 = blockIdx.x * 128, n0 = nt * 128;
  __shared__ __align__(16) bf16_t As[128 * 64];
  __shared__ __align__(16) bf16_t Bs[128 * 64];
  f32x4 acc[4][4];
#pragma unroll
  for (int i = 0; i < 4; ++i)
#pragma unroll
    for (int j = 0; j < 4; ++j) acc[i][j] = (f32x4){0.f, 0.f, 0.f, 0.f};

  gemm_core(Az, Bz, DD, DD, m0, n0, As, Bs, acc);

  const int tid = threadIdx.x, wave = tid >> 6, lane = tid & 63;
  const int l15 = lane & 15, quad = lane >> 4;
  const int wm = (wave & 1) * 64, wn = (wave >> 1) * 64;
  float* rsz = rs + (((size_t)z * 8 + nt) * 2 + (wave >> 1)) * LQ;
  const float scale = 0.04419417382415922f;  // 1/sqrt(512)

#pragma unroll
  for (int i = 0; i < 4; ++i)
#pragma unroll
    for (int r = 0; r < 4; ++r) {
      const int row = m0 + wm + i * 16 + quad * 4 + r;
      float rsum = 0.f;
#pragma unroll
      for (int j = 0; j < 4; ++j) {
        const int col = n0 + wn + j * 16 + l15;
        const int mv = mz[(size_t)row * LK + col];
        const float p = mv ? __expf(acc[i][j][r] * scale) : 0.f;
        rsum += p;
        Sz[(size_t)row * LK + col] = (bf16_t)p;
      }
      rsum += __shfl_xor(rsum, 1);
      rsum += __shfl_xor(rsum, 2);
      rsum += __shfl_xor(rsum, 4);
      rsum += __shfl_xor(rsum, 8);
      if (l15 == 0) rsz[row] = rsum;   // block+half-owned slot, no race
    }
}

// ---------------- pass 2: ctx = (S * inv_rowsum) . V ----------------
// R7 grid (8 mt, 4 nt, 16 z). inv computed in-prologue from 16 rs partials.
__global__ __launch_bounds__(256, 4) void gemm_pv(
    const bf16_t* __restrict__ S, const bf16_t* __restrict__ Vt,
    const float* __restrict__ rs, bf16_t* __restrict__ ctx)
{
  const int z = blockIdx.z, bb = z >> 3, hh = z & 7;
  const bf16_t* Az = S + (size_t)z * LQ * LK;
  const bf16_t* Bz = Vt + (size_t)z * DD * LK;
  bf16_t* Cz = ctx + (size_t)bb * LQ * (NH * DD) + (size_t)hh * DD;

  const int m0 = blockIdx.x * 128, n0 = blockIdx.y * 128;
  __shared__ __align__(16) bf16_t As[128 * 64];
  __shared__ __align__(16) bf16_t Bs[128 * 64];
  __shared__ float invs[128];

  const int tid = threadIdx.x;
  if (tid < 128) {   // rowsum reduce for this block's 128 rows
    const float* p = rs + (size_t)z * 16 * LQ + (m0 + tid);
    float tot = 0.f;
#pragma unroll
    for (int s = 0; s < 16; ++s) tot += p[s * LQ];
    invs[tid] = 1.f / tot;
  }
  // visibility guaranteed by gemm_core's internal barriers before epilogue

  f32x4 acc[4][4];
#pragma unroll
  for (int i = 0; i < 4; ++i)
#pragma unroll
    for (int j = 0; j < 4; ++j) acc[i][j] = (f32x4){0.f, 0.f, 0.f, 0.f};

  gemm_core(Az, Bz, LK, LK, m0, n0, As, Bs, acc);

  const int wave = tid >> 6, lane = tid & 63;
  const int l15 = lane & 15, quad = lane >> 4;
  const int wm = (wave & 1) * 64, wn = (wave >> 1) * 64;

#pragma unroll
  for (int i = 0; i < 4; ++i)
#pragma unroll
    for (int r = 0; r < 4; ++r) {
      const int lrow = wm + i * 16 + quad * 4 + r;
      const float iv = invs[lrow];
#pragma unroll
      for (int j = 0; j < 4; ++j) {
        const int col = n0 + wn + j * 16 + l15;
        Cz[(size_t)(m0 + lrow) * (NH * DD) + col] = (bf16_t)(acc[i][j][r] * iv);
      }
    }
}

// ---------------- out-projection, split-K=4 ----------------
// R7 grid (64 mt, 4 nt, 4 ks): same-m/different-n at stride 64 ≡ 0 mod 8 ->
// same XCD -> each ctx A-tile fetched once per XCD (FETCH 52 MB measured).
__global__ __launch_bounds__(256, 4) void gemm_outk(
    const bf16_t* __restrict__ ctx, const bf16_t* __restrict__ wp,
    float* __restrict__ partial)
{
  const int ks = blockIdx.z;
  const bf16_t* A = ctx + ks * 1024;
  const bf16_t* B = wp + ks * 1024;
  float* P = partial + (size_t)ks * B_DIM * LQ * DD;

  const int m0 = blockIdx.x * 128, n0 = blockIdx.y * 128;
  __shared__ __align__(16) bf16_t As[128 * 64];
  __shared__ __align__(16) bf16_t Bs[128 * 64];
  f32x4 acc[4][4];
#pragma unroll
  for (int i = 0; i < 4; ++i)
#pragma unroll
    for (int j = 0; j < 4; ++j) acc[i][j] = (f32x4){0.f, 0.f, 0.f, 0.f};

  gemm_core(A, B, NH * DD, 1024, m0, n0, As, Bs, acc);

  const int tid = threadIdx.x, wave = tid >> 6, lane = tid & 63;
  const int l15 = lane & 15, quad = lane >> 4;
  const int wm = (wave & 1) * 64, wn = (wave >> 1) * 64;
#pragma unroll
  for (int i = 0; i < 4; ++i)
#pragma unroll
    for (int j = 0; j < 4; ++j)
#pragma unroll
      for (int r = 0; r < 4; ++r) {
        const int row = m0 + wm + i * 16 + quad * 4 + r;
        const int col = n0 + wn + j * 16 + l15;
        P[(size_t)row * DD + col] = acc[i][j][r];
      }
}

__global__ void reduce_out(const float* __restrict__ p, const float* __restrict__ bp,
                           float* __restrict__ out) {
  const int N = B_DIM * LQ * DD;
  int i = (blockIdx.x * 256 + threadIdx.x) * 4;
  float4 a = *(const float4*)(p + i);
  float4 b = *(const float4*)(p + N + i);
  float4 c = *(const float4*)(p + 2 * N + i);
  float4 d = *(const float4*)(p + 3 * N + i);
  const float4 bb4 = *(const float4*)(bp + (i & 511));
  float4 r;
  r.x = a.x + b.x + c.x + d.x + bb4.x;
  r.y = a.y + b.y + c.y + d.y + bb4.y;
  r.z = a.z + b.z + c.z + d.z + bb4.z;
  r.w = a.w + b.w + c.w + d.w + bb4.w;
  *(float4*)(out + i) = r;
}

// ---------------- host launcher ----------------
extern "C" void kernel_launch(void* const* d_in, const int* in_sizes, int n_in,
                              void* d_out, int out_size, void* d_ws, size_t ws_size,
                              hipStream_t stream) {
  const float* x      = (const float*)d_in[0];
  const float* states = (const float*)d_in[1];
  const int*   mask   = (const int*)d_in[2];
  const float* Wq     = (const float*)d_in[3];
  const float* bq     = (const float*)d_in[4];
  const float* Wk     = (const float*)d_in[5];
  const float* bk     = (const float*)d_in[6];
  const float* Wv     = (const float*)d_in[7];
  const float* bv     = (const float*)d_in[8];
  const float* Wp     = (const float*)d_in[9];
  const float* bp     = (const float*)d_in[10];
  float* out = (float*)d_out;

  // Workspace layout (ends 164,626,432 B <= 167,772,160 B proven safe):
  //   ctx 64MB @ 0 ; wqb/wkb/wvb 4MB each @ 64M..76M
  //   Qc 16MB @ 76M ; Kc 16MB @ 92M ; Vtc 16MB @ 108M
  //   S 32MB @ 124M ; sbf (full states bf16) 8MB @ 156M
  //   out-proj fp32 partials (64MB) reuse Kc/Vtc/S after chunks
  // d_out (16MB fp32) as scratch until reduce_out overwrites all of it:
  //   rsum 1MB @ +0 ; wpb bf16 4MB @ +1MB ; xbf (full x bf16) 8MB @ +5MB
  char* ws = (char*)d_ws;
  bf16_t* ctxb = (bf16_t*)(ws + 0);
  bf16_t* wqb  = (bf16_t*)(ws + 67108864);
  bf16_t* wkb  = (bf16_t*)(ws + 71303168);
  bf16_t* wvb  = (bf16_t*)(ws + 75497472);
  bf16_t* Qc   = (bf16_t*)(ws + 79691776);
  bf16_t* Kc   = (bf16_t*)(ws + 96468992);
  bf16_t* Vtc  = (bf16_t*)(ws + 113246208);
  bf16_t* Sb   = (bf16_t*)(ws + 130023424);
  bf16_t* sbf  = (bf16_t*)(ws + 163577856);
  float*  pbuf = (float*)(ws + 96468992);           // dead Kc/Vtc/S after chunks
  float*  rsum = out;                               // 1MB
  bf16_t* wpb  = (bf16_t*)((char*)d_out + 1048576); // 4MB
  bf16_t* xbf  = (bf16_t*)((char*)d_out + 5242880); // 8MB

  const int n_w = NH * DD * DD;          // 2,097,152
  const int n_x = B_DIM * LQ * DD;       // 4,194,304

  // all conversions in one dispatch
  cvt_all<<<dim3(n_x / 1024, 6), 256, 0, stream>>>(
      Wq, Wk, Wv, Wp, x, states, wqb, wkb, wvb, wpb, xbf, sbf, n_w, n_x);

  for (int c = 0; c < NCH; ++c) {
    const bf16_t* xc = xbf + (size_t)c * LB * LQ * DD;
    const bf16_t* sc = sbf + (size_t)c * LB * LK * DD;
    const int* mc = mask + (size_t)c * LB * LQ * LK;
    bf16_t* ctxc = ctxb + (size_t)c * LB * LQ * (NH * DD);

    gemm_qkv<<<dim3(32, 48), 256, 0, stream>>>(
        xc, sc, wqb, wkb, wvb, bq, bk, bv, Qc, Kc, Vtc);

    gemm_qk<<<dim3(8, 8, LB * NH), 256, 0, stream>>>(Qc, Kc, mc, Sb, rsum);
    gemm_pv<<<dim3(8, 4, LB * NH), 256, 0, stream>>>(Sb, Vtc, rsum, ctxc);
  }

  // out = ctx @ Wp^T + bp : split-K=4 (1024 blocks) + reduce
  gemm_outk<<<dim3(64, 4, 4), 256, 0, stream>>>(ctxb, wpb, pbuf);
  reduce_out<<<(B_DIM * LQ * DD) / 1024, 256, 0, stream>>>(pbuf, bp, out);
}